// Round 10
// baseline (50.065 us; speedup 1.0000x reference)
//
#include <hip/hip_runtime.h>
#include <math.h>

// Problem constants
#define NBINS 2049       // F
#define NXC   599        // 2*NLAG-1
#define LST   640        // ws row stride (floats)
#define TWO_PI 6.283185307179586f

// complex LDS padding: +2 complex per 64; all hot accesses use hand-folded
// base + literal-offset forms (each verified against CPAD at sample points).
#define CPAD(c) ((c) + 2 * ((c) >> 6))

struct cpx { float r, i; };
__device__ inline cpx cmul(cpx a, cpx b) { return cpx{a.r * b.r - a.i * b.i, a.r * b.i + a.i * b.r}; }

__device__ inline void dft4i(float& r0, float& i0, float& r1, float& i1,
                             float& r2, float& i2, float& r3, float& i3) {
    float t0r = r0 + r2, t0i = i0 + i2;
    float t1r = r0 - r2, t1i = i0 - i2;
    float t2r = r1 + r3, t2i = i1 + i3;
    float t3r = r1 - r3, t3i = i1 - i3;
    r0 = t0r + t2r; i0 = t0i + t2i;
    r2 = t0r - t2r; i2 = t0i - t2i;
    r1 = t1r - t3i; i1 = t1i + t3r;
    r3 = t1r + t3i; i3 = t1i - t3r;
}

__device__ inline void radix8_bfly(float r[8], float im[8]) {
    float er0 = r[0], ei0 = im[0], er1 = r[2], ei1 = im[2];
    float er2 = r[4], ei2 = im[4], er3 = r[6], ei3 = im[6];
    float or0 = r[1], oi0 = im[1], or1 = r[3], oi1 = im[3];
    float or2 = r[5], oi2 = im[5], or3 = r[7], oi3 = im[7];
    dft4i(er0, ei0, er1, ei1, er2, ei2, er3, ei3);
    dft4i(or0, oi0, or1, oi1, or2, oi2, or3, oi3);
    const float C = 0.70710678118654752f;
    float w1r = C * (or1 - oi1), w1i = C * (or1 + oi1);
    float w2r = -oi2,            w2i = or2;
    float w3r = -C * (or3 + oi3), w3i = C * (or3 - oi3);
    r[0] = er0 + or0; im[0] = ei0 + oi0;
    r[4] = er0 - or0; im[4] = ei0 - oi0;
    r[1] = er1 + w1r; im[1] = ei1 + w1i;
    r[5] = er1 - w1r; im[5] = ei1 - w1i;
    r[2] = er2 + w2r; im[2] = ei2 + w2i;
    r[6] = er2 - w2r; im[6] = ei2 - w2i;
    r[3] = er3 + w3r; im[3] = ei3 + w3i;
    r[7] = er3 - w3r; im[7] = ei3 - w3i;
}

// Apply w^k (k=1..7), w = (cs, sn). Log-depth tree; 7 independent final multiplies.
__device__ inline void apply_tw7(float zr[8], float zi[8], float cs, float sn) {
    cpx w[8];
    w[1] = cpx{cs, sn};
    w[2] = cmul(w[1], w[1]);
    w[3] = cmul(w[1], w[2]);
    w[4] = cmul(w[2], w[2]);
    w[5] = cmul(w[2], w[3]);
    w[6] = cmul(w[3], w[3]);
    w[7] = cmul(w[3], w[4]);
#pragma unroll
    for (int k = 1; k < 8; ++k) {
        float a = zr[k] * w[k].r - zi[k] * w[k].i;
        float b = zr[k] * w[k].i + zi[k] * w[k].r;
        zr[k] = a; zi[k] = b;
    }
}

// Keep 4 float4s simultaneously live (input-only scalar constraints — the
// tied/indirect form is unsupported on gfx950). Forces distinct dest VGPRs
// and a clause of loads with one vmcnt drain.
#define KEEP_LIVE4(V0, V1, V2, V3) \
    asm volatile("" :: "v"((V0).x), "v"((V0).y), "v"((V0).z), "v"((V0).w), \
                       "v"((V1).x), "v"((V1).y), "v"((V1).z), "v"((V1).w), \
                       "v"((V2).x), "v"((V2).y), "v"((V2).z), "v"((V2).w), \
                       "v"((V3).x), "v"((V3).y), "v"((V3).z), "v"((V3).w))

// Kernel 1: one (b,c) row per 256-thread block (4 waves). In-place DIF chain
// radix 8/8/8/4 (spans 256/32/4/1). Phase 0: 8 float4 global loads (16B/lane),
// ALL forced simultaneously live → single vmcnt stall episode/wave;
// X staged to LDS (b128 pairs); pack reads own+mirror bins from LDS.
__global__ __launch_bounds__(256, 5) void k1_fft(const float2* __restrict__ d1,
                                                 const float2* __restrict__ d2,
                                                 float* __restrict__ ws) {
    __shared__ float2 S[2113];   // CPAD(0..2047) + slot 2112 (bin 2048); 16.9 KB
    const int row = blockIdx.x;  // b*128 + c
    const int tt = threadIdx.x;  // 0..255
    const float* p1 = (const float*)(d1 + (long)row * NBINS);
    const float* p2 = (const float*)(d2 + (long)row * NBINS);
    const float h = 2.44140625e-4f;   // 0.5/2048 (irfft scale folded into X)

    // folded LDS bases (each verified vs CPAD):
    const int pw = 2 * tt;
    const int PW = pw + 2 * (pw >> 6);                    // CPAD(2tt+512j)     = PW + 528j (and +1)
    const int PT = tt + 2 * (tt >> 6);                    // CPAD(tt+256j)      = PT + 264j
    const int PU = (2048 - tt) + 2 * ((2048 - tt) >> 6);  // CPAD(2048-tt-256j) = PU - 264j
    const int i2 = tt & 31;
    const int B2 = 264 * (tt >> 5) + i2;                  // CPAD(256(tt>>5)+i2+32j) = B2 + 32j + 2(j>>1)
    const int i3 = tt & 3;
    const int B3 = 32 * (tt >> 2) + 2 * (tt >> 3) + i3;   // CPAD(32(tt>>2)+i3+4j)   = B3 + 4j

    // ---- phase 0a: burst 8 dwordx4 loads (bins {2tt,2tt+1}+512j), force-live ----
    float4 A0, A1, A2, A3, B0, B1, B2v, B3v;
    {
        const float* q1 = p1 + 4 * tt;        // float idx 4tt = complex 2tt
        const float* q2 = p2 + 4 * tt;
        A0 = *(const float4*)(q1);            // complex 2tt, 2tt+1
        A1 = *(const float4*)(q1 + 1024);     // +512 complex
        A2 = *(const float4*)(q1 + 2048);
        A3 = *(const float4*)(q1 + 3072);
        B0 = *(const float4*)(q2);
        B1 = *(const float4*)(q2 + 1024);
        B2v = *(const float4*)(q2 + 2048);
        B3v = *(const float4*)(q2 + 3072);
    }
    float2 nyA, nyB;
    if (tt == 255) { nyA = ((const float2*)p1)[2048]; nyB = ((const float2*)p2)[2048]; }
    // All 32 result registers must be live here → loads issue as one clause.
    KEEP_LIVE4(A0, A1, A2, A3);
    KEEP_LIVE4(B0, B1, B2v, B3v);

    // ---- phase 0b: X = h*conj(c1)*c2 pairs → LDS via b128 ----
    {
        float x0r = h * (A0.x * B0.x + A0.y * B0.y);
        float x0i = h * (A0.x * B0.y - A0.y * B0.x);
        if (tt == 0) x0i = 0.0f;   // bin 0 imag zeroed (pocketfft c2r)
        float x1r = h * (A0.z * B0.z + A0.w * B0.w);
        float x1i = h * (A0.z * B0.w - A0.w * B0.z);
        *(float4*)&S[PW] = make_float4(x0r, x0i, x1r, x1i);
    }
    {
        float x0r = h * (A1.x * B1.x + A1.y * B1.y);
        float x0i = h * (A1.x * B1.y - A1.y * B1.x);
        float x1r = h * (A1.z * B1.z + A1.w * B1.w);
        float x1i = h * (A1.z * B1.w - A1.w * B1.z);
        *(float4*)&S[PW + 528] = make_float4(x0r, x0i, x1r, x1i);
    }
    {
        float x0r = h * (A2.x * B2v.x + A2.y * B2v.y);
        float x0i = h * (A2.x * B2v.y - A2.y * B2v.x);
        float x1r = h * (A2.z * B2v.z + A2.w * B2v.w);
        float x1i = h * (A2.z * B2v.w - A2.w * B2v.z);
        *(float4*)&S[PW + 1056] = make_float4(x0r, x0i, x1r, x1i);
    }
    {
        float x0r = h * (A3.x * B3v.x + A3.y * B3v.y);
        float x0i = h * (A3.x * B3v.y - A3.y * B3v.x);
        float x1r = h * (A3.z * B3v.z + A3.w * B3v.w);
        float x1i = h * (A3.z * B3v.w - A3.w * B3v.z);
        *(float4*)&S[PW + 1584] = make_float4(x0r, x0i, x1r, x1i);
    }
    if (tt == 255)   // bin 2048 (Nyquist), imag zeroed
        S[2112] = make_float2(h * (nyA.x * nyB.x + nyA.y * nyB.y), 0.0f);
    __syncthreads();

    // ---- pack: Z[c] = E + i*t_c*D; own X[tt+256j] and mirror X[2048-tt-256j] from LDS ----
    // t_c = e^{2pi i tt/4096} * e^{2pi i j/16} (j-factor literal table)
    const float WC8[8] = { 1.0f, 0.92387953251128675613f, 0.70710678118654752440f,
        0.38268343236508977173f, 0.0f, -0.38268343236508977173f,
        -0.70710678118654752440f, -0.92387953251128675613f };
    const float WS8[8] = { 0.0f, 0.38268343236508977173f, 0.70710678118654752440f,
        0.92387953251128675613f, 1.0f, 0.92387953251128675613f,
        0.70710678118654752440f, 0.38268343236508977173f };
    float zr[8], zi[8], sn, cs;
    __sincosf((float)tt * (TWO_PI / 4096.0f), &sn, &cs);
#pragma unroll
    for (int j = 0; j < 8; ++j) {
        float2 o = S[PT + 264 * j];
        float2 m = S[PU - 264 * j];   // tt=0,j=0 → slot 2112 (bin 2048)
        float er = o.x + m.x, ei = o.y - m.y;
        float dr = o.x - m.x, di = o.y + m.y;
        float twr = cs * WC8[j] - sn * WS8[j];
        float twi = cs * WS8[j] + sn * WC8[j];
        zr[j] = er - twi * dr - twr * di;
        zi[j] = ei + twr * dr - twi * di;
    }

    // ---- stage 1: L=2048, span=256, i=tt ----
    radix8_bfly(zr, zi);
    __sincosf((float)tt * (TWO_PI / 2048.0f), &sn, &cs);
    apply_tw7(zr, zi, cs, sn);
    __syncthreads();   // all pack reads complete before overwrite
#pragma unroll
    for (int k = 0; k < 8; ++k)
        S[PT + 264 * k] = make_float2(zr[k], zi[k]);
    __syncthreads();

    // ---- stage 2: L=256, span=32, i = tt&31; per-thread in-place ----
#pragma unroll
    for (int j = 0; j < 8; ++j) {
        float2 v = S[B2 + 32 * j + 2 * (j >> 1)];
        zr[j] = v.x; zi[j] = v.y;
    }
    radix8_bfly(zr, zi);
    __sincosf((float)i2 * (TWO_PI / 256.0f), &sn, &cs);
    apply_tw7(zr, zi, cs, sn);
#pragma unroll
    for (int k = 0; k < 8; ++k)
        S[B2 + 32 * k + 2 * (k >> 1)] = make_float2(zr[k], zi[k]);
    __syncthreads();

    // ---- stage 3: L=32, span=4, i = tt&3; per-thread in-place ----
#pragma unroll
    for (int j = 0; j < 8; ++j) {
        float2 v = S[B3 + 4 * j];
        zr[j] = v.x; zi[j] = v.y;
    }
    radix8_bfly(zr, zi);
    __sincosf((float)i3 * (TWO_PI / 32.0f), &sn, &cs);
    apply_tw7(zr, zi, cs, sn);
#pragma unroll
    for (int k = 0; k < 8; ++k)
        S[B3 + 4 * k] = make_float2(zr[k], zi[k]);
    __syncthreads();

    // ---- stage 4: radix-4, span=1, butterflies u = tt, tt+256 ----
    // output m = m0 + 512*k4 at pos 4u + k4, m0 = (u>>6)+8*((u>>3)&7)+64*(u&7).
    // Needed: k4=0 (y0): m0<=149 → Re l=2m0+299, Im l=2m0+300;
    //         k4=3 (y3): m0>=363 → Re l=2m0-725, Im l=2m0-724; m0==362 → Im l=0.
    float* wrow = ws + (long)row * LST;
#pragma unroll
    for (int hh = 0; hh < 2; ++hh) {
        const int u = tt + 256 * hh;
        const int cb = 4 * u + 2 * (u >> 4);   // CPAD(4u); 4u..4u+3 contiguous
        float4 v0 = *(const float4*)&S[cb];        // x0, x1
        float4 v1 = *(const float4*)&S[cb + 2];    // x2, x3
        float y0r = (v0.x + v1.x) + (v0.z + v1.z);
        float y0i = (v0.y + v1.y) + (v0.w + v1.w);
        float t1r = v0.x - v1.x, t1i = v0.y - v1.y;
        float t3r = v0.z - v1.z, t3i = v0.w - v1.w;
        float y3r = t1r + t3i, y3i = t1i - t3r;
        const int m0 = (u >> 6) + 8 * ((u >> 3) & 7) + 64 * (u & 7);
        if (m0 <= 149) { wrow[2 * m0 + 299] = y0r; wrow[2 * m0 + 300] = y0i; }
        if (m0 >= 363)      { wrow[2 * m0 - 725] = y3r; wrow[2 * m0 - 724] = y3i; }
        else if (m0 == 362) { wrow[0] = y3i; }
    }
}

// Kernel 2a: in-place prefix sum along channels. Thread owns (b, lag).
__global__ __launch_bounds__(128) void k2a_prefix(float* __restrict__ ws) {
    const int b = blockIdx.x / 5;
    const int l = (blockIdx.x % 5) * 128 + threadIdx.x;
    if (l >= NXC) return;
    float* base = ws + (long)b * 128 * LST + l;
    float run = 0.0f;
#pragma unroll 4
    for (int c = 0; c < 128; ++c) {
        run += base[c * LST];
        base[c * LST] = run;
    }
}

// Kernel 2b: windowed value from prefix difference, argmax/argmin with
// first-index tie-break, final cc/tshift + event passthrough.
__global__ __launch_bounds__(128) void k2b_pick(const float* __restrict__ ws,
                                                const int* __restrict__ e1,
                                                const int* __restrict__ e2,
                                                float* __restrict__ out) {
    const int bc = blockIdx.x;
    const int b = bc >> 7, c = bc & 127;
    const int t = threadIdx.x;
    const float* Pb = ws + (long)(b * 128) * LST;
    const float* hi = Pb + (long)min(c + 9, 127) * LST;
    const bool has_lo = (c >= 11);
    const float* lo = Pb + (long)(has_lo ? (c - 11) : 0) * LST;

    float vmax = -3.0e38f; int imax = 0;
    float vmin = 3.0e38f;  int imin = 0;
    for (int l = t; l < NXC; l += 128) {
        float s = hi[l] - (has_lo ? lo[l] : 0.0f);
        s *= (1.0f / 20.0f);
        if (s > vmax) { vmax = s; imax = l; }
        if (s < vmin) { vmin = s; imin = l; }
    }

    __shared__ float smax[128], smin[128];
    __shared__ int   sxi[128], sni[128];
    smax[t] = vmax; sxi[t] = imax; smin[t] = vmin; sni[t] = imin;
    __syncthreads();
    for (int off = 64; off > 0; off >>= 1) {
        if (t < off) {
            float v2 = smax[t + off]; int ii = sxi[t + off];
            if (v2 > smax[t] || (v2 == smax[t] && ii < sxi[t])) { smax[t] = v2; sxi[t] = ii; }
            float u2 = smin[t + off]; int jj = sni[t + off];
            if (u2 < smin[t] || (u2 == smin[t] && jj < sni[t])) { smin[t] = u2; sni[t] = jj; }
        }
        __syncthreads();
    }
    if (t == 0) {
        float vx = smax[0], vn = smin[0];
        int ix = sxi[0], in_ = sni[0];
        bool ineg = fabsf(vn) > vx;
        float ccv = ineg ? vn : vx;
        int idx = ineg ? in_ : ix;
        out[bc] = ccv;
        out[4096 + bc] = (float)(idx - 299) * 0.01f;   // (idx - NLAG + 1) * DT
    }
    if (bc == 0 && t < 32) out[8192 + t] = (float)e1[t];
    if (bc == 1 && t < 32) out[8224 + t] = (float)e2[t];
}

extern "C" void kernel_launch(void* const* d_in, const int* in_sizes, int n_in,
                              void* d_out, int out_size, void* d_ws, size_t ws_size,
                              hipStream_t stream) {
    const float2* d1 = (const float2*)d_in[0];
    const float2* d2 = (const float2*)d_in[1];
    const int* e1 = (const int*)d_in[2];
    const int* e2 = (const int*)d_in[3];
    float* out = (float*)d_out;
    float* ws = (float*)d_ws;

    k1_fft<<<dim3(4096), dim3(256), 0, stream>>>(d1, d2, ws);
    k2a_prefix<<<dim3(160), dim3(128), 0, stream>>>(ws);
    k2b_pick<<<dim3(4096), dim3(128), 0, stream>>>(ws, e1, e2, out);
}